// Round 5
// baseline (54.819 us; speedup 1.0000x reference)
//
#include <hip/hip_runtime.h>

#define BATCH 16
#define NCLS 80
#define FH 128
#define FW 128
#define HW (FH*FW)
#define MAXO 100
#define NOBJ (BATCH*MAXO)

#define SPLIT 4              // blocks per (b,c) channel
#define NPART (BATCH*NCLS*SPLIT)
#define PXB (HW/SPLIT)       // 4096 pixels per block
#define F4B (PXB/4)          // 1024 float4 per block
#define ROUNDS (F4B/256)     // 4 DMA rounds (each: 4 waves x 64 lanes x 16B)

typedef __attribute__((address_space(3))) void lds_void;
typedef const __attribute__((address_space(1))) void glb_void;

__device__ __forceinline__ float smooth_l1(float x) {
    const float F = 1.0f/9.0f;
    return (x >= F) ? (x - 0.5f*F) : (0.5f*x*x/F);
}

// Gaussian params for one annotation row. Returns false if invalid.
__device__ __forceinline__ bool obj_gauss(const float* a, float& cxi, float& cyi,
                                          float& r, float& coef, int& cls) {
    float clsf = a[4];
    if (!(clsf >= 0.0f)) { cls = -1; return false; }
    cls = (int)clsf;
    float x1 = fminf(fmaxf(a[0]*0.25f, 0.0f), (float)(FW-1));
    float y1 = fminf(fmaxf(a[1]*0.25f, 0.0f), (float)(FH-1));
    float x2 = fminf(fmaxf(a[2]*0.25f, 0.0f), (float)(FW-1));
    float y2 = fminf(fmaxf(a[3]*0.25f, 0.0f), (float)(FH-1));
    float bw = x2 - x1, bh = y2 - y1;
    cxi = truncf((x1 + x2)*0.5f);
    cyi = truncf((y1 + y2)*0.5f);
    float h = ceilf(bh), w = ceilf(bw);
    const float MO = 0.7f;
    float b1 = h + w;
    float c1 = w*h*(1.0f - MO)/(1.0f + MO);
    float r1 = (b1 + sqrtf(b1*b1 - 4.0f*c1))*0.5f;
    float b2 = 2.0f*(h + w);
    float c2 = (1.0f - MO)*w*h;
    float r2 = (b2 + sqrtf(b2*b2 - 16.0f*c2))*0.5f;
    float a3 = 4.0f*MO;
    float b3 = -2.0f*MO*(h + w);
    float c3 = (MO - 1.0f)*w*h;
    float r3 = (b3 + sqrtf(b3*b3 - 4.0f*a3*c3))/(2.0f*a3);
    r = fmaxf(0.0f, truncf(fminf(fminf(r1, r2), r3)));
    float sigma = (2.0f*r + 1.0f)/6.0f;
    coef = -1.0f/(2.0f*sigma*sigma);
    return true;
}

// SPLIT blocks per (b,c) channel. Heat tile staged into LDS via async
// global_load_lds DMA (issued FIRST, no VGPR round-trip, stays in flight
// while the per-class object list is built from annotations). Then compute
// entirely out of LDS. One (pos,neg,num) partial per block, no atomics.
__launch_bounds__(256)
__global__ void focal_kernel(const float4* __restrict__ heat,
                             const float*  __restrict__ annot,
                             float4*       __restrict__ part)
{
    int blk = blockIdx.x;
    int chan = blk / SPLIT;           // (b*NCLS + c)
    int partid = blk - chan*SPLIT;
    int b = chan / NCLS;
    int c = chan - b*NCLS;

    __shared__ float tile[PXB];       // 16 KB heat tile
    __shared__ float sx[MAXO], sy[MAXO], sr[MAXO], sk[MAXO];
    __shared__ int scnt;
    __shared__ float wred[3][4];

    int tid = threadIdx.x;
    int w = tid >> 6, lane = tid & 63;

    // 1) Issue all tile DMA up front: wave-uniform LDS base + lane*16,
    //    per-lane global source (m97 pattern, width=16 literal).
    const float4* hp = heat + (size_t)chan*(HW/4) + (size_t)partid*F4B;
    #pragma unroll
    for (int r2 = 0; r2 < ROUNDS; ++r2) {
        int qb = r2*256 + w*64;       // wave-uniform float4 base index
        __builtin_amdgcn_global_load_lds((glb_void*)(hp + qb + lane),
                                         (lds_void*)&tile[(size_t)qb*4],
                                         16, 0, 0);
    }

    // 2) Build per-class object list while DMA is in flight.
    if (tid == 0) scnt = 0;
    __syncthreads();
    if (tid < MAXO) {
        const float* a = annot + ((size_t)b*MAXO + tid)*5;
        float cxi, cyi, r, coef; int cls;
        if (obj_gauss(a, cxi, cyi, r, coef, cls) && cls == c) {
            int s = atomicAdd(&scnt, 1);
            sx[s] = cxi; sy[s] = cyi; sr[s] = r; sk[s] = coef;
        }
    }
    asm volatile("s_waitcnt vmcnt(0)" ::: "memory");  // this wave's DMA done
    __syncthreads();                                  // everyone's DMA + lists done
    int cnt = scnt;

    // 3) Compute from LDS.
    int pixbase = partid*PXB;
    float ploss = 0.0f, nloss = 0.0f, pnum = 0.0f;
    #pragma unroll
    for (int it = 0; it < ROUNDS; ++it) {
        int q = it*256 + tid;
        float4 h4 = ((const float4*)tile)[q];   // ds_read_b128
        int pix = pixbase + q*4;
        float fy = (float)(pix >> 7);
        float fx0 = (float)(pix & (FW-1));
        float hv[4] = {h4.x, h4.y, h4.z, h4.w};
        #pragma unroll
        for (int k = 0; k < 4; ++k) {
            float fx = fx0 + (float)k;
            float gmax = 0.0f;
            for (int j = 0; j < cnt; ++j) {
                float dx = fx - sx[j], dy = fy - sy[j];
                float r = sr[j];
                if (fabsf(dx) <= r && fabsf(dy) <= r) {
                    gmax = fmaxf(gmax, __expf(sk[j]*(dx*dx + dy*dy)));
                }
            }
            float p = fminf(fmaxf(hv[k], 1.0e-4f), 1.0f - 1.0e-4f);
            if (gmax == 1.0f) {
                float om = 1.0f - p;
                ploss += -__logf(p)*om*om;
                pnum += 1.0f;
            } else {
                float og = 1.0f - gmax;
                float w2 = og*og;
                nloss += -__logf(1.0f - p)*p*p*(w2*w2);
            }
        }
    }

    // 4) Block reduction, one float4 partial per block.
    #pragma unroll
    for (int off = 32; off > 0; off >>= 1) {
        ploss += __shfl_down(ploss, off);
        nloss += __shfl_down(nloss, off);
        pnum  += __shfl_down(pnum,  off);
    }
    if (lane == 0) { wred[0][w] = ploss; wred[1][w] = nloss; wred[2][w] = pnum; }
    __syncthreads();
    if (tid == 0) {
        float P = 0.0f, N = 0.0f, Q = 0.0f;
        #pragma unroll
        for (int i = 0; i < 4; ++i) { P += wred[0][i]; N += wred[1][i]; Q += wred[2][i]; }
        part[blk] = make_float4(P, N, Q, 0.0f);
    }
}

// Reduce focal partials + per-object target math + smooth-L1 gathers. One block.
__launch_bounds__(256)
__global__ void reg_kernel(const float* __restrict__ offp,
                           const float* __restrict__ whp,
                           const float* __restrict__ annot,
                           const float4* __restrict__ part,
                           float*        __restrict__ out)
{
    float P = 0.0f, N = 0.0f, Q = 0.0f;
    for (int i = threadIdx.x; i < NPART; i += blockDim.x) {
        float4 v = part[i];
        P += v.x; N += v.y; Q += v.z;
    }
    float loff = 0.0f, lwh = 0.0f, n = 0.0f;
    for (int o = threadIdx.x; o < NOBJ; o += blockDim.x) {
        int b = o / MAXO;
        const float* a = annot + (size_t)o*5;
        float clsf = a[4];
        float m = (clsf >= 0.0f) ? 1.0f : 0.0f;
        float x1 = fminf(fmaxf(a[0]*0.25f, 0.0f), (float)(FW-1));
        float y1 = fminf(fmaxf(a[1]*0.25f, 0.0f), (float)(FH-1));
        float x2 = fminf(fmaxf(a[2]*0.25f, 0.0f), (float)(FW-1));
        float y2 = fminf(fmaxf(a[3]*0.25f, 0.0f), (float)(FH-1));
        float cx = (x1 + x2)*0.5f, cy = (y1 + y2)*0.5f;
        float cxi = truncf(cx), cyi = truncf(cy);
        float tx = (cx - cxi)*m, ty = (cy - cyi)*m;
        float tw = (x2 - x1)*m, th = (y2 - y1)*m;
        int idx = (int)((cyi*(float)FW + cxi)*m);
        const float* ob = offp + (size_t)b*2*HW;
        const float* wb = whp  + (size_t)b*2*HW;
        float p0 = ob[idx], p1 = ob[HW + idx];
        float q0 = wb[idx], q1 = wb[HW + idx];
        loff += smooth_l1(fabsf(p0*m - tx*m)) + smooth_l1(fabsf(p1*m - ty*m));
        lwh  += smooth_l1(fabsf(q0*m - tw*m)) + smooth_l1(fabsf(q1*m - th*m));
        n += m;
    }
    __shared__ float wred[6][4];
    #pragma unroll
    for (int off = 32; off > 0; off >>= 1) {
        P    += __shfl_down(P,    off);
        N    += __shfl_down(N,    off);
        Q    += __shfl_down(Q,    off);
        loff += __shfl_down(loff, off);
        lwh  += __shfl_down(lwh,  off);
        n    += __shfl_down(n,    off);
    }
    int lane = threadIdx.x & 63, wid = threadIdx.x >> 6;
    if (lane == 0) {
        wred[0][wid] = P; wred[1][wid] = N; wred[2][wid] = Q;
        wred[3][wid] = loff; wred[4][wid] = lwh; wred[5][wid] = n;
    }
    __syncthreads();
    if (threadIdx.x == 0) {
        float s[6];
        #pragma unroll
        for (int r = 0; r < 6; ++r) {
            s[r] = wred[r][0] + wred[r][1] + wred[r][2] + wred[r][3];
        }
        float pn = s[2];
        float hm = (pn > 0.0f) ? (s[0] + s[1])/fmaxf(pn, 1.0f) : 0.0f;
        float ol = (s[5] > 0.0f) ? s[3]/fmaxf(s[5], 1.0f) : 0.0f;
        float wl = (s[5] > 0.0f) ? s[4]/fmaxf(s[5], 1.0f) : 0.0f;
        out[0] = 1.0f*hm;   // HM_W
        out[1] = 1.0f*ol;   // OFF_W
        out[2] = 0.1f*wl;   // WH_W
    }
}

extern "C" void kernel_launch(void* const* d_in, const int* in_sizes, int n_in,
                              void* d_out, int out_size, void* d_ws, size_t ws_size,
                              hipStream_t stream) {
    const float* heat  = (const float*)d_in[0];  // (16,80,128,128)
    const float* offp  = (const float*)d_in[1];  // (16,2,128,128)
    const float* whp   = (const float*)d_in[2];  // (16,2,128,128)
    const float* annot = (const float*)d_in[3];  // (16,100,5)
    float* out = (float*)d_out;                  // (3,)

    float4* part = (float4*)d_ws;                // NPART partials

    focal_kernel<<<NPART, 256, 0, stream>>>((const float4*)heat, annot, part);
    reg_kernel<<<1, 256, 0, stream>>>(offp, whp, annot, part, out);
}

// Round 6
// 46.256 us; speedup vs baseline: 1.1851x; 1.1851x over previous
//
#include <hip/hip_runtime.h>

#define BATCH 16
#define NCLS 80
#define FH 128
#define FW 128
#define HW (FH*FW)
#define MAXO 100
#define NOBJ (BATCH*MAXO)

#define NB1 2048                       // streaming blocks
#define F4TOT (BATCH*NCLS*HW/4)        // 5,242,880 float4
#define F4BLK (F4TOT/NB1)              // 2560 float4 per block (contiguous)
#define F4THR (F4BLK/256)              // 10 float4 per thread
#define NBLK (NB1 + NOBJ)              // + one correction block per object

__device__ __forceinline__ float smooth_l1(float x) {
    const float F = 1.0f/9.0f;
    return (x >= F) ? (x - 0.5f*F) : (0.5f*x*x/F);
}

__device__ __forceinline__ float bg_term(float h) {
    float p = fminf(fmaxf(h, 1.0e-4f), 1.0f - 1.0e-4f);
    return -__logf(1.0f - p) * p * p;
}

// Gaussian params for one annotation row (zeros + cls=-1 if invalid).
__device__ __forceinline__ void obj_gauss(const float* a, float& cxi, float& cyi,
                                          float& r, float& coef, int& cls) {
    float clsf = a[4];
    if (!(clsf >= 0.0f)) { cls = -1; cxi = cyi = r = 0.0f; coef = -1.0f; return; }
    cls = (int)clsf;
    float x1 = fminf(fmaxf(a[0]*0.25f, 0.0f), (float)(FW-1));
    float y1 = fminf(fmaxf(a[1]*0.25f, 0.0f), (float)(FH-1));
    float x2 = fminf(fmaxf(a[2]*0.25f, 0.0f), (float)(FW-1));
    float y2 = fminf(fmaxf(a[3]*0.25f, 0.0f), (float)(FH-1));
    float bw = x2 - x1, bh = y2 - y1;
    cxi = truncf((x1 + x2)*0.5f);
    cyi = truncf((y1 + y2)*0.5f);
    float h = ceilf(bh), w = ceilf(bw);
    const float MO = 0.7f;
    float b1 = h + w;
    float c1 = w*h*(1.0f - MO)/(1.0f + MO);
    float r1 = (b1 + sqrtf(b1*b1 - 4.0f*c1))*0.5f;
    float b2 = 2.0f*(h + w);
    float c2 = (1.0f - MO)*w*h;
    float r2 = (b2 + sqrtf(b2*b2 - 16.0f*c2))*0.5f;
    float a3 = 4.0f*MO;
    float b3 = -2.0f*MO*(h + w);
    float c3 = (MO - 1.0f)*w*h;
    float r3 = (b3 + sqrtf(b3*b3 - 4.0f*a3*c3))/(2.0f*a3);
    r = fmaxf(0.0f, truncf(fminf(fminf(r1, r2), r3)));
    float sigma = (2.0f*r + 1.0f)/6.0f;
    coef = -1.0f/(2.0f*sigma*sigma);
}

// blk < NB1 : background stream — sum bg_term over a contiguous 2560-float4 slab.
// blk >= NB1: correction — object o replaces bg_term with the true focal term
//             on its (2r+1)^2 box, deduped by lowest-index ownership.
__launch_bounds__(256)
__global__ void focal_kernel(const float4* __restrict__ heat,
                             const float*  __restrict__ annot,
                             float4*       __restrict__ part)
{
    int blk = blockIdx.x;
    int tid = threadIdx.x;
    __shared__ float sx[MAXO], sy[MAXO], sr[MAXO], sk[MAXO];
    __shared__ int scls[MAXO];
    __shared__ float wred[2][4];

    float acc = 0.0f, pnum = 0.0f;

    if (blk < NB1) {
        const float4* hp = heat + (size_t)blk*F4BLK + tid;
        #pragma unroll
        for (int i = 0; i < F4THR; ++i) {
            float4 h4 = hp[i*256];
            acc += bg_term(h4.x) + bg_term(h4.y) + bg_term(h4.z) + bg_term(h4.w);
        }
    } else {
        int o = blk - NB1;
        int b = o / MAXO;
        int oi = o - b*MAXO;
        if (tid < MAXO) {
            const float* a = annot + ((size_t)b*MAXO + tid)*5;
            float cxi, cyi, r, coef; int cls;
            obj_gauss(a, cxi, cyi, r, coef, cls);
            sx[tid] = cxi; sy[tid] = cyi; sr[tid] = r; sk[tid] = coef; scls[tid] = cls;
        }
        __syncthreads();
        int c = scls[oi];
        if (c >= 0) {
            int cxo = (int)sx[oi], cyo = (int)sy[oi];
            int r = (int)sr[oi];
            int side = 2*r + 1;
            int npx = side*side;
            const float* hc = (const float*)heat + (size_t)(b*NCLS + c)*HW;
            for (int pi = tid; pi < npx; pi += 256) {
                int px = cxo - r + (pi % side);
                int py = cyo - r + (pi / side);
                if (px < 0 || px >= FW || py < 0 || py >= FH) continue;
                float fpx = (float)px, fpy = (float)py;
                float gmax = 0.0f;
                bool owner = true;
                for (int j = 0; j < MAXO; ++j) {
                    if (scls[j] != c) continue;
                    float dx = fpx - sx[j], dy = fpy - sy[j];
                    if (fabsf(dx) <= sr[j] && fabsf(dy) <= sr[j]) {
                        if (j < oi) { owner = false; break; }
                        gmax = fmaxf(gmax, __expf(sk[j]*(dx*dx + dy*dy)));
                    }
                }
                if (!owner) continue;
                float h = hc[py*FW + px];
                float p = fminf(fmaxf(h, 1.0e-4f), 1.0f - 1.0e-4f);
                float bg = -__logf(1.0f - p) * p * p;   // bitwise == streaming term
                if (gmax == 1.0f) {
                    float om = 1.0f - p;
                    acc += -__logf(p)*om*om - bg;
                    pnum += 1.0f;
                } else {
                    float og = 1.0f - gmax;
                    float w2 = og*og;
                    acc += bg*(w2*w2 - 1.0f);
                }
            }
        }
    }

    #pragma unroll
    for (int off = 32; off > 0; off >>= 1) {
        acc  += __shfl_down(acc,  off);
        pnum += __shfl_down(pnum, off);
    }
    int lane = tid & 63, wid = tid >> 6;
    if (lane == 0) { wred[0][wid] = acc; wred[1][wid] = pnum; }
    __syncthreads();
    if (tid == 0) {
        float A = 0.0f, Q = 0.0f;
        #pragma unroll
        for (int i = 0; i < 4; ++i) { A += wred[0][i]; Q += wred[1][i]; }
        part[blk] = make_float4(A, Q, 0.0f, 0.0f);
    }
}

// Reduce focal partials + per-object target math + smooth-L1 gathers. One block.
__launch_bounds__(256)
__global__ void reg_kernel(const float* __restrict__ offp,
                           const float* __restrict__ whp,
                           const float* __restrict__ annot,
                           const float4* __restrict__ part,
                           float*        __restrict__ out)
{
    float P = 0.0f, Q = 0.0f;
    for (int i = threadIdx.x; i < NBLK; i += blockDim.x) {
        float4 v = part[i];
        P += v.x; Q += v.y;
    }
    float loff = 0.0f, lwh = 0.0f, n = 0.0f;
    for (int o = threadIdx.x; o < NOBJ; o += blockDim.x) {
        int b = o / MAXO;
        const float* a = annot + (size_t)o*5;
        float clsf = a[4];
        float m = (clsf >= 0.0f) ? 1.0f : 0.0f;
        float x1 = fminf(fmaxf(a[0]*0.25f, 0.0f), (float)(FW-1));
        float y1 = fminf(fmaxf(a[1]*0.25f, 0.0f), (float)(FH-1));
        float x2 = fminf(fmaxf(a[2]*0.25f, 0.0f), (float)(FW-1));
        float y2 = fminf(fmaxf(a[3]*0.25f, 0.0f), (float)(FH-1));
        float cx = (x1 + x2)*0.5f, cy = (y1 + y2)*0.5f;
        float cxi = truncf(cx), cyi = truncf(cy);
        float tx = (cx - cxi)*m, ty = (cy - cyi)*m;
        float tw = (x2 - x1)*m, th = (y2 - y1)*m;
        int idx = (int)((cyi*(float)FW + cxi)*m);
        const float* ob = offp + (size_t)b*2*HW;
        const float* wb = whp  + (size_t)b*2*HW;
        float p0 = ob[idx], p1 = ob[HW + idx];
        float q0 = wb[idx], q1 = wb[HW + idx];
        loff += smooth_l1(fabsf(p0*m - tx*m)) + smooth_l1(fabsf(p1*m - ty*m));
        lwh  += smooth_l1(fabsf(q0*m - tw*m)) + smooth_l1(fabsf(q1*m - th*m));
        n += m;
    }
    __shared__ float wred[5][4];
    #pragma unroll
    for (int off = 32; off > 0; off >>= 1) {
        P    += __shfl_down(P,    off);
        Q    += __shfl_down(Q,    off);
        loff += __shfl_down(loff, off);
        lwh  += __shfl_down(lwh,  off);
        n    += __shfl_down(n,    off);
    }
    int lane = threadIdx.x & 63, wid = threadIdx.x >> 6;
    if (lane == 0) {
        wred[0][wid] = P; wred[1][wid] = Q;
        wred[2][wid] = loff; wred[3][wid] = lwh; wred[4][wid] = n;
    }
    __syncthreads();
    if (threadIdx.x == 0) {
        float s[5];
        #pragma unroll
        for (int r = 0; r < 5; ++r) {
            s[r] = wred[r][0] + wred[r][1] + wred[r][2] + wred[r][3];
        }
        float pn = s[1];
        float hm = (pn > 0.0f) ? s[0]/fmaxf(pn, 1.0f) : 0.0f;
        float ol = (s[4] > 0.0f) ? s[2]/fmaxf(s[4], 1.0f) : 0.0f;
        float wl = (s[4] > 0.0f) ? s[3]/fmaxf(s[4], 1.0f) : 0.0f;
        out[0] = 1.0f*hm;   // HM_W
        out[1] = 1.0f*ol;   // OFF_W
        out[2] = 0.1f*wl;   // WH_W
    }
}

extern "C" void kernel_launch(void* const* d_in, const int* in_sizes, int n_in,
                              void* d_out, int out_size, void* d_ws, size_t ws_size,
                              hipStream_t stream) {
    const float* heat  = (const float*)d_in[0];  // (16,80,128,128)
    const float* offp  = (const float*)d_in[1];  // (16,2,128,128)
    const float* whp   = (const float*)d_in[2];  // (16,2,128,128)
    const float* annot = (const float*)d_in[3];  // (16,100,5)
    float* out = (float*)d_out;                  // (3,)

    float4* part = (float4*)d_ws;                // NBLK partials

    focal_kernel<<<NBLK, 256, 0, stream>>>((const float4*)heat, annot, part);
    reg_kernel<<<1, 256, 0, stream>>>(offp, whp, annot, part, out);
}

// Round 7
// 37.569 us; speedup vs baseline: 1.4592x; 1.2312x over previous
//
#include <hip/hip_runtime.h>

#define BATCH 16
#define NCLS 80
#define FH 128
#define FW 128
#define HW (FH*FW)
#define MAXO 100
#define NOBJ (BATCH*MAXO)

#define NB1 2048                       // streaming blocks
#define F4TOT (BATCH*NCLS*HW/4)        // 5,242,880 float4
#define F4BLK (F4TOT/NB1)              // 2560 float4 per block (contiguous)
#define F4THR (F4BLK/256)              // 10 float4 per thread
#define NREG (NOBJ/64)                 // 25 reg-gather blocks (64 obj each)
#define NBLK (NB1 + NOBJ + NREG)       // streaming + corrections + reg gathers

__device__ __forceinline__ float smooth_l1(float x) {
    const float F = 1.0f/9.0f;
    return (x >= F) ? (x - 0.5f*F) : (0.5f*x*x/F);
}

__device__ __forceinline__ float bg_term(float h) {
    float p = fminf(fmaxf(h, 1.0e-4f), 1.0f - 1.0e-4f);
    return -__logf(1.0f - p) * p * p;
}

// Gaussian params for one annotation row (zeros + cls=-1 if invalid).
__device__ __forceinline__ void obj_gauss(const float* a, float& cxi, float& cyi,
                                          float& r, float& coef, int& cls) {
    float clsf = a[4];
    if (!(clsf >= 0.0f)) { cls = -1; cxi = cyi = r = 0.0f; coef = -1.0f; return; }
    cls = (int)clsf;
    float x1 = fminf(fmaxf(a[0]*0.25f, 0.0f), (float)(FW-1));
    float y1 = fminf(fmaxf(a[1]*0.25f, 0.0f), (float)(FH-1));
    float x2 = fminf(fmaxf(a[2]*0.25f, 0.0f), (float)(FW-1));
    float y2 = fminf(fmaxf(a[3]*0.25f, 0.0f), (float)(FH-1));
    float bw = x2 - x1, bh = y2 - y1;
    cxi = truncf((x1 + x2)*0.5f);
    cyi = truncf((y1 + y2)*0.5f);
    float h = ceilf(bh), w = ceilf(bw);
    const float MO = 0.7f;
    float b1 = h + w;
    float c1 = w*h*(1.0f - MO)/(1.0f + MO);
    float r1 = (b1 + sqrtf(b1*b1 - 4.0f*c1))*0.5f;
    float b2 = 2.0f*(h + w);
    float c2 = (1.0f - MO)*w*h;
    float r2 = (b2 + sqrtf(b2*b2 - 16.0f*c2))*0.5f;
    float a3 = 4.0f*MO;
    float b3 = -2.0f*MO*(h + w);
    float c3 = (MO - 1.0f)*w*h;
    float r3 = (b3 + sqrtf(b3*b3 - 4.0f*a3*c3))/(2.0f*a3);
    r = fmaxf(0.0f, truncf(fminf(fminf(r1, r2), r3)));
    float sigma = (2.0f*r + 1.0f)/6.0f;
    coef = -1.0f/(2.0f*sigma*sigma);
}

// blk < NB1                : background stream over a 2560-float4 slab -> (acc, pnum)
// NB1 <= blk < NB1+NOBJ    : per-object focal correction               -> (acc, pnum)
// blk >= NB1+NOBJ          : 64-object smooth-L1 gather                -> (loff, lwh, n)
__launch_bounds__(256)
__global__ void focal_kernel(const float4* __restrict__ heat,
                             const float*  __restrict__ annot,
                             const float*  __restrict__ offp,
                             const float*  __restrict__ whp,
                             float4*       __restrict__ part)
{
    int blk = blockIdx.x;
    int tid = threadIdx.x;
    __shared__ float sx[MAXO], sy[MAXO], sr[MAXO], sk[MAXO];
    __shared__ int scls[MAXO];
    __shared__ float wred[3][4];

    float v0 = 0.0f, v1 = 0.0f, v2 = 0.0f;   // (acc, pnum, -) or (loff, lwh, n)

    if (blk < NB1) {
        const float4* hp = heat + (size_t)blk*F4BLK + tid;
        #pragma unroll
        for (int i = 0; i < F4THR; ++i) {
            float4 h4 = hp[i*256];
            v0 += bg_term(h4.x) + bg_term(h4.y) + bg_term(h4.z) + bg_term(h4.w);
        }
    } else if (blk < NB1 + NOBJ) {
        int o = blk - NB1;
        int b = o / MAXO;
        int oi = o - b*MAXO;
        if (tid < MAXO) {
            const float* a = annot + ((size_t)b*MAXO + tid)*5;
            float cxi, cyi, r, coef; int cls;
            obj_gauss(a, cxi, cyi, r, coef, cls);
            sx[tid] = cxi; sy[tid] = cyi; sr[tid] = r; sk[tid] = coef; scls[tid] = cls;
        }
        __syncthreads();
        int c = scls[oi];
        if (c >= 0) {
            int cxo = (int)sx[oi], cyo = (int)sy[oi];
            int r = (int)sr[oi];
            int side = 2*r + 1;
            int npx = side*side;
            const float* hc = (const float*)heat + (size_t)(b*NCLS + c)*HW;
            for (int pi = tid; pi < npx; pi += 256) {
                int px = cxo - r + (pi % side);
                int py = cyo - r + (pi / side);
                if (px < 0 || px >= FW || py < 0 || py >= FH) continue;
                float fpx = (float)px, fpy = (float)py;
                float gmax = 0.0f;
                bool owner = true;
                for (int j = 0; j < MAXO; ++j) {
                    if (scls[j] != c) continue;
                    float dx = fpx - sx[j], dy = fpy - sy[j];
                    if (fabsf(dx) <= sr[j] && fabsf(dy) <= sr[j]) {
                        if (j < oi) { owner = false; break; }
                        gmax = fmaxf(gmax, __expf(sk[j]*(dx*dx + dy*dy)));
                    }
                }
                if (!owner) continue;
                float h = hc[py*FW + px];
                float p = fminf(fmaxf(h, 1.0e-4f), 1.0f - 1.0e-4f);
                float bg = -__logf(1.0f - p) * p * p;   // bitwise == streaming term
                if (gmax == 1.0f) {
                    float om = 1.0f - p;
                    v0 += -__logf(p)*om*om - bg;
                    v1 += 1.0f;
                } else {
                    float og = 1.0f - gmax;
                    float w2 = og*og;
                    v0 += bg*(w2*w2 - 1.0f);
                }
            }
        }
    } else {
        // 64 objects per block, one object per lane of wave 0.
        int rb = blk - (NB1 + NOBJ);
        if (tid < 64) {
            int o = rb*64 + tid;
            int b = o / MAXO;
            const float* a = annot + (size_t)o*5;
            float clsf = a[4];
            float m = (clsf >= 0.0f) ? 1.0f : 0.0f;
            float x1 = fminf(fmaxf(a[0]*0.25f, 0.0f), (float)(FW-1));
            float y1 = fminf(fmaxf(a[1]*0.25f, 0.0f), (float)(FH-1));
            float x2 = fminf(fmaxf(a[2]*0.25f, 0.0f), (float)(FW-1));
            float y2 = fminf(fmaxf(a[3]*0.25f, 0.0f), (float)(FH-1));
            float cx = (x1 + x2)*0.5f, cy = (y1 + y2)*0.5f;
            float cxi = truncf(cx), cyi = truncf(cy);
            float tx = (cx - cxi)*m, ty = (cy - cyi)*m;
            float tw = (x2 - x1)*m, th = (y2 - y1)*m;
            int idx = (int)((cyi*(float)FW + cxi)*m);
            const float* ob = offp + (size_t)b*2*HW;
            const float* wb = whp  + (size_t)b*2*HW;
            float p0 = ob[idx], p1 = ob[HW + idx];
            float q0 = wb[idx], q1 = wb[HW + idx];
            v0 = smooth_l1(fabsf(p0*m - tx*m)) + smooth_l1(fabsf(p1*m - ty*m));
            v1 = smooth_l1(fabsf(q0*m - tw*m)) + smooth_l1(fabsf(q1*m - th*m));
            v2 = m;
        }
    }

    #pragma unroll
    for (int off = 32; off > 0; off >>= 1) {
        v0 += __shfl_down(v0, off);
        v1 += __shfl_down(v1, off);
        v2 += __shfl_down(v2, off);
    }
    int lane = tid & 63, wid = tid >> 6;
    if (lane == 0) { wred[0][wid] = v0; wred[1][wid] = v1; wred[2][wid] = v2; }
    __syncthreads();
    if (tid == 0) {
        float A = 0.0f, B2 = 0.0f, C2 = 0.0f;
        #pragma unroll
        for (int i = 0; i < 4; ++i) { A += wred[0][i]; B2 += wred[1][i]; C2 += wred[2][i]; }
        part[blk] = make_float4(A, B2, C2, 0.0f);
    }
}

// Final combine: reduce all partials, apply normalizations. One block.
__launch_bounds__(256)
__global__ void finalize_kernel(const float4* __restrict__ part,
                                float*        __restrict__ out)
{
    float P = 0.0f, Q = 0.0f;           // focal acc, pos_num
    float LO = 0.0f, LW = 0.0f, NN = 0.0f;
    for (int i = threadIdx.x; i < NB1 + NOBJ; i += blockDim.x) {
        float4 v = part[i];
        P += v.x; Q += v.y;
    }
    for (int i = NB1 + NOBJ + threadIdx.x; i < NBLK; i += blockDim.x) {
        float4 v = part[i];
        LO += v.x; LW += v.y; NN += v.z;
    }
    __shared__ float wred[5][4];
    #pragma unroll
    for (int off = 32; off > 0; off >>= 1) {
        P  += __shfl_down(P,  off);
        Q  += __shfl_down(Q,  off);
        LO += __shfl_down(LO, off);
        LW += __shfl_down(LW, off);
        NN += __shfl_down(NN, off);
    }
    int lane = threadIdx.x & 63, wid = threadIdx.x >> 6;
    if (lane == 0) {
        wred[0][wid] = P; wred[1][wid] = Q;
        wred[2][wid] = LO; wred[3][wid] = LW; wred[4][wid] = NN;
    }
    __syncthreads();
    if (threadIdx.x == 0) {
        float s[5];
        #pragma unroll
        for (int r = 0; r < 5; ++r) {
            s[r] = wred[r][0] + wred[r][1] + wred[r][2] + wred[r][3];
        }
        float pn = s[1];
        float hm = (pn > 0.0f) ? s[0]/fmaxf(pn, 1.0f) : 0.0f;
        float ol = (s[4] > 0.0f) ? s[2]/fmaxf(s[4], 1.0f) : 0.0f;
        float wl = (s[4] > 0.0f) ? s[3]/fmaxf(s[4], 1.0f) : 0.0f;
        out[0] = 1.0f*hm;   // HM_W
        out[1] = 1.0f*ol;   // OFF_W
        out[2] = 0.1f*wl;   // WH_W
    }
}

extern "C" void kernel_launch(void* const* d_in, const int* in_sizes, int n_in,
                              void* d_out, int out_size, void* d_ws, size_t ws_size,
                              hipStream_t stream) {
    const float* heat  = (const float*)d_in[0];  // (16,80,128,128)
    const float* offp  = (const float*)d_in[1];  // (16,2,128,128)
    const float* whp   = (const float*)d_in[2];  // (16,2,128,128)
    const float* annot = (const float*)d_in[3];  // (16,100,5)
    float* out = (float*)d_out;                  // (3,)

    float4* part = (float4*)d_ws;                // NBLK partials

    focal_kernel<<<NBLK, 256, 0, stream>>>((const float4*)heat, annot, offp, whp, part);
    finalize_kernel<<<1, 256, 0, stream>>>(part, out);
}

// Round 8
// 30.262 us; speedup vs baseline: 1.8115x; 1.2414x over previous
//
#include <hip/hip_runtime.h>

#define BATCH 16
#define NCLS 80
#define FH 128
#define FW 128
#define HW (FH*FW)
#define MAXO 100
#define NOBJ (BATCH*MAXO)

#define NB1 2048                       // streaming blocks
#define F4TOT (BATCH*NCLS*HW/4)        // 5,242,880 float4
#define F4BLK (F4TOT/NB1)              // 2560 float4 per block (contiguous)
#define F4THR (F4BLK/256)              // 10 float4 per thread
#define NREG (NOBJ/64)                 // 25 reg-gather blocks (64 obj each)
#define NSMALL (NOBJ + NREG)           // small blocks go FIRST (no tail)
#define NBLK (NSMALL + NB1)

__device__ __forceinline__ float smooth_l1(float x) {
    const float F = 1.0f/9.0f;
    return (x >= F) ? (x - 0.5f*F) : (0.5f*x*x/F);
}

__device__ __forceinline__ float bg_term(float h) {
    float p = fminf(fmaxf(h, 1.0e-4f), 1.0f - 1.0e-4f);
    return -__logf(1.0f - p) * p * p;
}

// Gaussian params for one annotation row (zeros + cls=-1 if invalid).
__device__ __forceinline__ void obj_gauss(const float* a, float& cxi, float& cyi,
                                          float& r, float& coef, int& cls) {
    float clsf = a[4];
    if (!(clsf >= 0.0f)) { cls = -1; cxi = cyi = r = 0.0f; coef = -1.0f; return; }
    cls = (int)clsf;
    float x1 = fminf(fmaxf(a[0]*0.25f, 0.0f), (float)(FW-1));
    float y1 = fminf(fmaxf(a[1]*0.25f, 0.0f), (float)(FH-1));
    float x2 = fminf(fmaxf(a[2]*0.25f, 0.0f), (float)(FW-1));
    float y2 = fminf(fmaxf(a[3]*0.25f, 0.0f), (float)(FH-1));
    float bw = x2 - x1, bh = y2 - y1;
    cxi = truncf((x1 + x2)*0.5f);
    cyi = truncf((y1 + y2)*0.5f);
    float h = ceilf(bh), w = ceilf(bw);
    const float MO = 0.7f;
    float b1 = h + w;
    float c1 = w*h*(1.0f - MO)/(1.0f + MO);
    float r1 = (b1 + sqrtf(b1*b1 - 4.0f*c1))*0.5f;
    float b2 = 2.0f*(h + w);
    float c2 = (1.0f - MO)*w*h;
    float r2 = (b2 + sqrtf(b2*b2 - 16.0f*c2))*0.5f;
    float a3 = 4.0f*MO;
    float b3 = -2.0f*MO*(h + w);
    float c3 = (MO - 1.0f)*w*h;
    float r3 = (b3 + sqrtf(b3*b3 - 4.0f*a3*c3))/(2.0f*a3);
    r = fmaxf(0.0f, truncf(fminf(fminf(r1, r2), r3)));
    float sigma = (2.0f*r + 1.0f)/6.0f;
    coef = -1.0f/(2.0f*sigma*sigma);
}

// blk < NOBJ            : per-object focal correction          -> (acc, pnum, 0)
// NOBJ <= blk < NSMALL  : 64-object smooth-L1 gather           -> (loff, lwh, n)
// blk >= NSMALL         : background stream over 2560 float4   -> (acc, 0, 0)
__launch_bounds__(256)
__global__ void focal_kernel(const float4* __restrict__ heat,
                             const float*  __restrict__ annot,
                             const float*  __restrict__ offp,
                             const float*  __restrict__ whp,
                             float4*       __restrict__ part)
{
    int blk = blockIdx.x;
    int tid = threadIdx.x;
    __shared__ float sx[MAXO], sy[MAXO], sr[MAXO], sk[MAXO];
    __shared__ int scls[MAXO];
    __shared__ float wred[3][4];

    float v0 = 0.0f, v1 = 0.0f, v2 = 0.0f;

    if (blk >= NSMALL) {
        // ---- background stream with explicit 2-deep prefetch pipeline ----
        const float4* hp = heat + (size_t)(blk - NSMALL)*F4BLK + tid;
        float4 cur = hp[0];
        #pragma unroll
        for (int i = 0; i < F4THR; ++i) {
            float4 nxt = make_float4(0.f, 0.f, 0.f, 0.f);
            if (i + 1 < F4THR) nxt = hp[(i+1)*256];   // issue next load early
            v0 += bg_term(cur.x) + bg_term(cur.y) + bg_term(cur.z) + bg_term(cur.w);
            cur = nxt;
        }
    } else if (blk < NOBJ) {
        // ---- per-object correction ----
        int o = blk;
        int b = o / MAXO;
        int oi = o - b*MAXO;
        if (tid < MAXO) {
            const float* a = annot + ((size_t)b*MAXO + tid)*5;
            float cxi, cyi, r, coef; int cls;
            obj_gauss(a, cxi, cyi, r, coef, cls);
            sx[tid] = cxi; sy[tid] = cyi; sr[tid] = r; sk[tid] = coef; scls[tid] = cls;
        }
        __syncthreads();
        int c = scls[oi];
        if (c >= 0) {
            int cxo = (int)sx[oi], cyo = (int)sy[oi];
            int r = (int)sr[oi];
            int side = 2*r + 1;
            int npx = side*side;
            const float* hc = (const float*)heat + (size_t)(b*NCLS + c)*HW;
            for (int pi = tid; pi < npx; pi += 256) {
                int px = cxo - r + (pi % side);
                int py = cyo - r + (pi / side);
                if (px < 0 || px >= FW || py < 0 || py >= FH) continue;
                float fpx = (float)px, fpy = (float)py;
                float gmax = 0.0f;
                bool owner = true;
                for (int j = 0; j < MAXO; ++j) {
                    if (scls[j] != c) continue;
                    float dx = fpx - sx[j], dy = fpy - sy[j];
                    if (fabsf(dx) <= sr[j] && fabsf(dy) <= sr[j]) {
                        if (j < oi) { owner = false; break; }
                        gmax = fmaxf(gmax, __expf(sk[j]*(dx*dx + dy*dy)));
                    }
                }
                if (!owner) continue;
                float h = hc[py*FW + px];
                float p = fminf(fmaxf(h, 1.0e-4f), 1.0f - 1.0e-4f);
                float bg = -__logf(1.0f - p) * p * p;   // bitwise == streaming term
                if (gmax == 1.0f) {
                    float om = 1.0f - p;
                    v0 += -__logf(p)*om*om - bg;
                    v1 += 1.0f;
                } else {
                    float og = 1.0f - gmax;
                    float w2 = og*og;
                    v0 += bg*(w2*w2 - 1.0f);
                }
            }
        }
    } else {
        // ---- 64-object smooth-L1 gather ----
        int rb = blk - NOBJ;
        if (tid < 64) {
            int o = rb*64 + tid;
            int b = o / MAXO;
            const float* a = annot + (size_t)o*5;
            float clsf = a[4];
            float m = (clsf >= 0.0f) ? 1.0f : 0.0f;
            float x1 = fminf(fmaxf(a[0]*0.25f, 0.0f), (float)(FW-1));
            float y1 = fminf(fmaxf(a[1]*0.25f, 0.0f), (float)(FH-1));
            float x2 = fminf(fmaxf(a[2]*0.25f, 0.0f), (float)(FW-1));
            float y2 = fminf(fmaxf(a[3]*0.25f, 0.0f), (float)(FH-1));
            float cx = (x1 + x2)*0.5f, cy = (y1 + y2)*0.5f;
            float cxi = truncf(cx), cyi = truncf(cy);
            float tx = (cx - cxi)*m, ty = (cy - cyi)*m;
            float tw = (x2 - x1)*m, th = (y2 - y1)*m;
            int idx = (int)((cyi*(float)FW + cxi)*m);
            const float* ob = offp + (size_t)b*2*HW;
            const float* wb = whp  + (size_t)b*2*HW;
            float p0 = ob[idx], p1 = ob[HW + idx];
            float q0 = wb[idx], q1 = wb[HW + idx];
            v0 = smooth_l1(fabsf(p0*m - tx*m)) + smooth_l1(fabsf(p1*m - ty*m));
            v1 = smooth_l1(fabsf(q0*m - tw*m)) + smooth_l1(fabsf(q1*m - th*m));
            v2 = m;
        }
    }

    #pragma unroll
    for (int off = 32; off > 0; off >>= 1) {
        v0 += __shfl_down(v0, off);
        v1 += __shfl_down(v1, off);
        v2 += __shfl_down(v2, off);
    }
    int lane = tid & 63, wid = tid >> 6;
    if (lane == 0) { wred[0][wid] = v0; wred[1][wid] = v1; wred[2][wid] = v2; }
    __syncthreads();
    if (tid == 0) {
        float A = 0.0f, B2 = 0.0f, C2 = 0.0f;
        #pragma unroll
        for (int i = 0; i < 4; ++i) { A += wred[0][i]; B2 += wred[1][i]; C2 += wred[2][i]; }
        part[blk] = make_float4(A, B2, C2, 0.0f);
    }
}

// Final combine: reduce all partials, apply normalizations. One block.
__launch_bounds__(256)
__global__ void finalize_kernel(const float4* __restrict__ part,
                                float*        __restrict__ out)
{
    float P = 0.0f, Q = 0.0f;           // focal acc, pos_num
    float LO = 0.0f, LW = 0.0f, NN = 0.0f;
    // corrections [0,NOBJ) and streaming [NSMALL,NBLK) carry (acc,pnum)
    for (int i = threadIdx.x; i < NOBJ; i += blockDim.x) {
        float4 v = part[i];
        P += v.x; Q += v.y;
    }
    for (int i = NSMALL + threadIdx.x; i < NBLK; i += blockDim.x) {
        float4 v = part[i];
        P += v.x; Q += v.y;
    }
    // reg blocks [NOBJ,NSMALL) carry (loff,lwh,n)
    for (int i = NOBJ + threadIdx.x; i < NSMALL; i += blockDim.x) {
        float4 v = part[i];
        LO += v.x; LW += v.y; NN += v.z;
    }
    __shared__ float wred[5][4];
    #pragma unroll
    for (int off = 32; off > 0; off >>= 1) {
        P  += __shfl_down(P,  off);
        Q  += __shfl_down(Q,  off);
        LO += __shfl_down(LO, off);
        LW += __shfl_down(LW, off);
        NN += __shfl_down(NN, off);
    }
    int lane = threadIdx.x & 63, wid = threadIdx.x >> 6;
    if (lane == 0) {
        wred[0][wid] = P; wred[1][wid] = Q;
        wred[2][wid] = LO; wred[3][wid] = LW; wred[4][wid] = NN;
    }
    __syncthreads();
    if (threadIdx.x == 0) {
        float s[5];
        #pragma unroll
        for (int r = 0; r < 5; ++r) {
            s[r] = wred[r][0] + wred[r][1] + wred[r][2] + wred[r][3];
        }
        float pn = s[1];
        float hm = (pn > 0.0f) ? s[0]/fmaxf(pn, 1.0f) : 0.0f;
        float ol = (s[4] > 0.0f) ? s[2]/fmaxf(s[4], 1.0f) : 0.0f;
        float wl = (s[4] > 0.0f) ? s[3]/fmaxf(s[4], 1.0f) : 0.0f;
        out[0] = 1.0f*hm;   // HM_W
        out[1] = 1.0f*ol;   // OFF_W
        out[2] = 0.1f*wl;   // WH_W
    }
}

extern "C" void kernel_launch(void* const* d_in, const int* in_sizes, int n_in,
                              void* d_out, int out_size, void* d_ws, size_t ws_size,
                              hipStream_t stream) {
    const float* heat  = (const float*)d_in[0];  // (16,80,128,128)
    const float* offp  = (const float*)d_in[1];  // (16,2,128,128)
    const float* whp   = (const float*)d_in[2];  // (16,2,128,128)
    const float* annot = (const float*)d_in[3];  // (16,100,5)
    float* out = (float*)d_out;                  // (3,)

    float4* part = (float4*)d_ws;                // NBLK partials

    focal_kernel<<<NBLK, 256, 0, stream>>>((const float4*)heat, annot, offp, whp, part);
    finalize_kernel<<<1, 256, 0, stream>>>(part, out);
}